// Round 4
// baseline (609.774 us; speedup 1.0000x reference)
//
#include <hip/hip_runtime.h>
#include <hip/hip_bf16.h>
#include <cstdint>
#include <cstddef>

#define M_TOTAL 16384   // WORLD_SIZE * M_LOCAL
#define K_DIM   4096
#define N_DIM   4096

typedef __attribute__((ext_vector_type(8))) short s16x8;
typedef __attribute__((ext_vector_type(4))) float f32x4;
typedef __attribute__((ext_vector_type(16))) float f32x16;
typedef unsigned short ushort_t;

// ---------- fp32 -> bf16 round-to-nearest-even ----------
__device__ __forceinline__ ushort_t f2bf(float x) {
  unsigned u = __float_as_uint(x);
  return (ushort_t)((u + 0x7fffu + ((u >> 16) & 1u)) >> 16);
}

// ---------- cast A [M,K] fp32 -> bf16, 8 elems/thread ----------
__global__ __launch_bounds__(256) void cast_kernel(const float* __restrict__ in,
                                                   ushort_t* __restrict__ out,
                                                   long n8) {
  long i = (long)blockIdx.x * 256 + threadIdx.x;
  if (i >= n8) return;
  const f32x4* p = (const f32x4*)in + i * 2;
  f32x4 a = p[0], b = p[1];
  union { s16x8 v; ushort_t u[8]; } r;
  r.u[0] = f2bf(a.x); r.u[1] = f2bf(a.y); r.u[2] = f2bf(a.z); r.u[3] = f2bf(a.w);
  r.u[4] = f2bf(b.x); r.u[5] = f2bf(b.y); r.u[6] = f2bf(b.z); r.u[7] = f2bf(b.w);
  *((s16x8*)out + i) = r.v;
}

// ---------- transpose+cast W [K,N] fp32 -> Bt [N,K] bf16 ----------
__global__ __launch_bounds__(256) void transpose_cast_kernel(const float* __restrict__ B,
                                                             ushort_t* __restrict__ Bt) {
  __shared__ float tile[64][65];
  int nbx = N_DIM / 64;
  int n0 = (blockIdx.x % nbx) * 64;
  int k0 = (blockIdx.x / nbx) * 64;
  int tx = threadIdx.x & 63;
  int ty = threadIdx.x >> 6;
#pragma unroll
  for (int i = 0; i < 64; i += 4)
    tile[ty + i][tx] = B[(size_t)(k0 + ty + i) * N_DIM + n0 + tx];
  __syncthreads();
#pragma unroll
  for (int i = 0; i < 64; i += 4)
    Bt[(size_t)(n0 + ty + i) * K_DIM + k0 + tx] = f2bf(tile[tx][ty + i]);
}

// ============================================================================
// 256x256 8-phase bf16 GEMM — round 4: MFMA shape 16x16x32 -> 32x32x16
// (2495 vs 2176 TF ubench ceiling: -14.7% matrix-pipe time, half issue slots).
// Staging ledger / vmcnt / barriers / LDS byte-layout IDENTICAL to round 2/3.
// Wave owns 128x64 = 4(M) x 2(N) frags of 32x32. Per phase: one quadrant
// (2 mf x 1 nf) x K=64 (4 ks of K16) = 8 MFMA. Reads per phase: 12/4/8/0 b128.
// A-frag: row = q*64+mf*32+(l&31); slot = ks*2+(l>>5); phys = slot^(row&7).
// C/D 32x32 layout: col=lane&31, row=(reg&3)+8*(reg>>2)+4*(lane>>5) [m74/m101].
// ============================================================================
#define BM 256
#define BN 256
#define BK 64
#define NTILE (K_DIM / BK)   // 64 -> 32 iterations, last peeled

__device__ __forceinline__ void load_lds16(const ushort_t* g, ushort_t* l) {
  __builtin_amdgcn_global_load_lds(
      (const __attribute__((address_space(1))) unsigned int*)g,
      (__attribute__((address_space(3))) unsigned int*)l, 16, 0, 0);
}

#define BAR __builtin_amdgcn_s_barrier()
#define VMW4 asm volatile("s_waitcnt vmcnt(4)" ::: "memory")
#define VMW0 asm volatile("s_waitcnt vmcnt(0)" ::: "memory")

#define STAGE_A(dst, h, t) do { \
    load_lds16(pA + (size_t)((h) * 128) * K_DIM + (t) * 64, (dst) + (h) * 8192); \
    load_lds16(pA + (size_t)((h) * 128 + 64) * K_DIM + (t) * 64, (dst) + (h) * 8192 + 4096); } while (0)
#define STAGE_B(dst, h, t) do { \
    load_lds16(pB + (size_t)((h) * 128) * K_DIM + (t) * 64, (dst) + (h) * 8192); \
    load_lds16(pB + (size_t)((h) * 128 + 64) * K_DIM + (t) * 64, (dst) + (h) * 8192 + 4096); } while (0)

// A reads: 2 frags (mf) x 4 ks. Slot XOR trick: phys slot for ks = base ^ (ks<<1)
// -> ushort index ^ (ks*16). Offsets q*4096 (+64 rows), mf*2048 (+32 rows).
#define READ_A32(buf, arr, q) do { \
    _Pragma("unroll") for (int mf = 0; mf < 2; ++mf) \
    _Pragma("unroll") for (int ks = 0; ks < 4; ++ks) \
      arr[mf][ks] = *(const s16x8*)&lds[buf][((aBase + (q) * 4096 + mf * 2048) ^ (ks * 16))]; } while (0)
// B reads: 1 frag (nf = nh) x 4 ks.
#define READ_B32(buf, arr, nh) do { \
    _Pragma("unroll") for (int ks = 0; ks < 4; ++ks) \
      arr[ks] = *(const s16x8*)&lds[buf][((bBase + (nh) * 2048) ^ (ks * 16))]; } while (0)

// 8 MFMA per phase: ks-outer, 2 independent accs round-robin.
#define MFMA_Q32(arr_a, arr_b, im0, nf) do { \
    __builtin_amdgcn_s_setprio(1); \
    _Pragma("unroll") for (int ks = 0; ks < 4; ++ks) \
    _Pragma("unroll") for (int mf = 0; mf < 2; ++mf) \
      acc[(im0) + mf][nf] = __builtin_amdgcn_mfma_f32_32x32x16_bf16( \
          arr_a[mf][ks], arr_b[ks], acc[(im0) + mf][nf], 0, 0, 0); \
    __builtin_amdgcn_s_setprio(0); } while (0)

__global__ __launch_bounds__(512, 2)
void gemm_8phase(const ushort_t* __restrict__ A, const ushort_t* __restrict__ Bt,
                 const float* __restrict__ bias, float* __restrict__ C) {
  __shared__ ushort_t lds[2][32768];  // [buf][ A: 0..16383 | B: 16384..32767 ]

  // bijective XCD swizzle (nwg = 1024, % 8 == 0)
  int nwg = gridDim.x;
  int wg  = blockIdx.x;
  int swz = (wg & 7) * (nwg >> 3) + (wg >> 3);
  int bm = (swz >> 4) << 8;
  int bn = (swz & 15) << 8;

  int tid = threadIdx.x;
  int wid = tid >> 6;
  int l   = tid & 63;
  int wm = wid >> 2, wn = wid & 3;

  // staging: lane covers global (row = base + wid*8 + (l>>3), slot = (l&7)^(row&7))
  int sg8 = ((l & 7) ^ ((l >> 3) & 7)) << 3;
  const ushort_t* pA = A  + (size_t)(bm + wid * 8 + (l >> 3)) * K_DIM + sg8;
  const ushort_t* pB = Bt + (size_t)(bn + wid * 8 + (l >> 3)) * K_DIM + sg8;
  ushort_t* sA0 = &lds[0][wid * 512];
  ushort_t* sA1 = &lds[1][wid * 512];
  ushort_t* sB0 = &lds[0][16384 + wid * 512];
  ushort_t* sB1 = &lds[1][16384 + wid * 512];

  // read bases (32x32 frags): row = wm*128 + (l&31); base slot = (l>>5) ^ (l&7)
  int slotA = (l >> 5) ^ (l & 7);
  int aBase = (wm * 128 + (l & 31)) * 64 + slotA * 8;
  int bBase = 16384 + (wn * 64 + (l & 31)) * 64 + slotA * 8;

  f32x16 acc[4][2];
#pragma unroll
  for (int im = 0; im < 4; ++im)
#pragma unroll
    for (int nf = 0; nf < 2; ++nf)
#pragma unroll
      for (int e = 0; e < 16; ++e) acc[im][nf][e] = 0.f;

  s16x8 a[2][4], b0[4], b1[4];

  // prologue: tile0 full (8 issues), tile1 B halves (4 issues); drain tile0
  STAGE_B(sB0, 0, 0); STAGE_B(sB0, 1, 0);
  STAGE_A(sA0, 0, 0); STAGE_A(sA0, 1, 0);
  STAGE_B(sB1, 0, 1); STAGE_B(sB1, 1, 1);
  VMW4; BAR;

  for (int j = 0; j < NTILE / 2 - 1; ++j) {   // j = 0..30, tiles 0..61
    int t1 = 2 * j + 1, t2 = 2 * j + 2, t3 = 2 * j + 3;
    // P1: A-q0, B-n0 -> acc[0..1][0]
    READ_A32(0, a, 0); READ_B32(0, b0, 0);
    STAGE_A(sA1, 0, t1);
    BAR; MFMA_Q32(a, b0, 0, 0); BAR;
    // P2: B-n1 -> acc[0..1][1]
    READ_B32(0, b1, 1);
    STAGE_A(sA1, 1, t1);
    BAR; MFMA_Q32(a, b1, 0, 1); BAR;
    // P3: A-q1 -> acc[2..3][1]
    READ_A32(0, a, 1);
    STAGE_B(sB0, 0, t2);
    BAR; MFMA_Q32(a, b1, 2, 1); BAR;
    // P4: -> acc[2..3][0]
    STAGE_B(sB0, 1, t2);
    BAR; MFMA_Q32(a, b0, 2, 0); VMW4; BAR;
    // P5
    READ_A32(1, a, 0); READ_B32(1, b0, 0);
    STAGE_A(sA0, 0, t2);
    BAR; MFMA_Q32(a, b0, 0, 0); BAR;
    // P6
    READ_B32(1, b1, 1);
    STAGE_A(sA0, 1, t2);
    BAR; MFMA_Q32(a, b1, 0, 1); BAR;
    // P7
    READ_A32(1, a, 1);
    STAGE_B(sB1, 0, t3);
    BAR; MFMA_Q32(a, b1, 2, 1); BAR;
    // P8
    STAGE_B(sB1, 1, t3);
    BAR; MFMA_Q32(a, b0, 2, 0); VMW4; BAR;
  }

  // tail: tiles 62 (buf0), 63 (buf1); t63 A still staged at P1,P2
  {
    READ_A32(0, a, 0); READ_B32(0, b0, 0);
    STAGE_A(sA1, 0, 63);
    BAR; MFMA_Q32(a, b0, 0, 0); BAR;

    READ_B32(0, b1, 1);
    STAGE_A(sA1, 1, 63);
    BAR; MFMA_Q32(a, b1, 0, 1); BAR;

    READ_A32(0, a, 1);
    BAR; MFMA_Q32(a, b1, 2, 1); BAR;

    BAR; MFMA_Q32(a, b0, 2, 0); VMW0; BAR;   // t63 A+B fully landed

    READ_A32(1, a, 0); READ_B32(1, b0, 0);
    BAR; MFMA_Q32(a, b0, 0, 0); BAR;

    READ_B32(1, b1, 1);
    BAR; MFMA_Q32(a, b1, 0, 1); BAR;

    READ_A32(1, a, 1);
    BAR; MFMA_Q32(a, b1, 2, 1); BAR;

    BAR; MFMA_Q32(a, b0, 2, 0);
  }

  // epilogue: 32x32 C/D layout col=lane&31, row=(reg&3)+8*(reg>>2)+4*(lane>>5)
  int rBase = bm + wm * 128 + 4 * (l >> 5);
  int cBase = bn + wn * 64 + (l & 31);
#pragma unroll
  for (int nf = 0; nf < 2; ++nf) {
    int c = cBase + nf * 32;
    float bv = bias[c];
#pragma unroll
    for (int im = 0; im < 4; ++im) {
#pragma unroll
      for (int r = 0; r < 16; ++r) {
        int row = rBase + im * 32 + (r & 3) + 8 * (r >> 2);
        C[(size_t)row * N_DIM + c] = acc[im][nf][r] + bv;
      }
    }
  }
}

// ---------- naive fp32 fallback (only if ws_size too small) ----------
__global__ __launch_bounds__(256)
void gemm_naive(const float* __restrict__ A, const float* __restrict__ B,
                const float* __restrict__ bias, float* __restrict__ C) {
  __shared__ float As[64][17];
  __shared__ float Bs[16][65];
  int nbn = N_DIM / 64;
  int m0 = (blockIdx.x / nbn) * 64;
  int n0 = (blockIdx.x % nbn) * 64;
  int tid = threadIdx.x;
  int tx = tid & 15, ty = tid >> 4;
  float acc[4][4] = {};
  for (int k0 = 0; k0 < K_DIM; k0 += 16) {
    __syncthreads();
#pragma unroll
    for (int e = tid * 4, i = 0; i < 4; ++i) {
      int idx = e + i;
      int r = idx >> 4, k = idx & 15;
      As[r][k] = A[(size_t)(m0 + r) * K_DIM + k0 + k];
    }
#pragma unroll
    for (int e = tid * 4, i = 0; i < 4; ++i) {
      int idx = e + i;
      int k = idx >> 6, n = idx & 63;
      Bs[k][n] = B[(size_t)(k0 + k) * N_DIM + n0 + n];
    }
    __syncthreads();
#pragma unroll
    for (int kk = 0; kk < 16; ++kk)
#pragma unroll
      for (int i = 0; i < 4; ++i)
#pragma unroll
        for (int j = 0; j < 4; ++j)
          acc[i][j] += As[ty * 4 + i][kk] * Bs[kk][tx * 4 + j];
  }
#pragma unroll
  for (int i = 0; i < 4; ++i)
#pragma unroll
    for (int j = 0; j < 4; ++j) {
      int r = m0 + ty * 4 + i, c = n0 + tx * 4 + j;
      C[(size_t)r * N_DIM + c] = acc[i][j] + bias[c];
    }
}

extern "C" void kernel_launch(void* const* d_in, const int* in_sizes, int n_in,
                              void* d_out, int out_size, void* d_ws, size_t ws_size,
                              hipStream_t stream) {
  const float* A32  = (const float*)d_in[0];
  const float* W32  = (const float*)d_in[1];
  const float* bias = (const float*)d_in[2];
  float* C = (float*)d_out;

  const size_t needA = (size_t)M_TOTAL * K_DIM * sizeof(ushort_t); // 128 MiB
  const size_t needB = (size_t)N_DIM * K_DIM * sizeof(ushort_t);   // 32 MiB

  if (ws_size >= needA + needB) {
    ushort_t* Abf = (ushort_t*)d_ws;
    ushort_t* Btb = (ushort_t*)((char*)d_ws + needA);
    long n8 = (long)M_TOTAL * K_DIM / 8;
    cast_kernel<<<(int)((n8 + 255) / 256), 256, 0, stream>>>(A32, Abf, n8);
    transpose_cast_kernel<<<(K_DIM / 64) * (N_DIM / 64), 256, 0, stream>>>(W32, Btb);
    gemm_8phase<<<(M_TOTAL / BM) * (N_DIM / BN), 512, 0, stream>>>(Abf, Btb, bias, C);
  } else {
    gemm_naive<<<(M_TOTAL / 64) * (N_DIM / 64), 256, 0, stream>>>(A32, W32, bias, C);
  }
}